// Round 5
// baseline (419.993 us; speedup 1.0000x reference)
//
#include <hip/hip_runtime.h>

// FNO2d fully fused: lin_in -> 4 spectral+conv layers -> lin_out in ONE kernel.
// Key fact: full-mode spectral conv == pair-local mixing (p paired with -p mod 256),
// so the whole network is local on pixel pairs; h never goes to global memory.
// R5: occupancy 2->3 blocks/CU (launch_bounds(256,3)) + layer-3 peel to shrink
//     main-loop register live range (pp/pq only live in the peeled tail).
#define W2_FLOATS   131072     // 4 layers * 2 (E,F) * 128*128  (fp32, special path uses E')
#define RB_FLOATS   131072     // 4 layers * 256 cols * 128 ch
#define WBF_USHORTS 262144     // 4 layers * 4 chunks * 16384 (split-bf16 B-operand layout)

typedef short s8v __attribute__((ext_vector_type(8)));   // 8 bf16 (4 VGPRs)
typedef float f4v __attribute__((ext_vector_type(4)));   // MFMA acc

__device__ __forceinline__ float gelu_f(float x) {
    return 0.5f * x * (1.0f + erff(x * 0.7071067811865476f));
}
__device__ __forceinline__ unsigned short bf16_rne(float v) {
    unsigned u = __float_as_uint(v);
    unsigned r = u + 0x7FFFu + ((u >> 16) & 1u);
    return (unsigned short)(r >> 16);
}
__device__ __forceinline__ float bf16_tof(unsigned short x) {
    return __uint_as_float(((unsigned)x) << 16);
}

// W2[l][which][i][o] = 0.5*(cw[l][o][i] + (which? wi : wr)[l][i][o])  (fp32, special path)
__global__ void prep_weights(const float* __restrict__ wr, const float* __restrict__ wi,
                             const float* __restrict__ cw, float* __restrict__ W2) {
    int idx = blockIdx.x * 256 + threadIdx.x;       // 131072
    int l = idx >> 15;
    int which = (idx >> 14) & 1;
    int i = (idx >> 7) & 127;
    int o = idx & 127;
    const float* w = which ? wi : wr;
    W2[idx] = 0.5f * (cw[(l << 14) + (o << 7) + i] + w[(l << 14) + (i << 7) + o]);
}

// Split-bf16 weights in B-operand layout.
// Wbf[l][kc][mat][half][quad][col][j]; k = kc*32 + quad*8 + j (input ch), col = out ch.
__global__ void prep_weights_bf16(const float* __restrict__ wr, const float* __restrict__ wi,
                                  const float* __restrict__ cw, unsigned short* __restrict__ Wbf) {
    int t = blockIdx.x * 256 + threadIdx.x;         // 131072 = 4*4*2*4*128*8
    int j    = t & 7;
    int col  = (t >> 3) & 127;
    int quad = (t >> 10) & 3;
    int m2   = (t >> 12) & 1;
    int kc   = (t >> 13) & 3;
    int l    = t >> 15;
    int k = kc * 32 + quad * 8 + j;
    const float* w = m2 ? wi : wr;
    float v = 0.5f * (cw[(l << 14) + (col << 7) + k] + w[(l << 14) + (k << 7) + col]);
    unsigned short hi = bf16_rne(v);
    unsigned short lo = bf16_rne(v - bf16_tof(hi));
    int base = (l * 4 + kc) * 16384;
    int idx_hi = base + (((m2 * 2 + 0) * 4 + quad) * 128 + col) * 8 + j;
    int idx_lo = base + (((m2 * 2 + 1) * 4 + quad) * 128 + col) * 8 + j;
    Wbf[idx_hi] = hi;
    Wbf[idx_lo] = lo;
}

// RB[l][c][o]: spatial map of the per-frequency constant bias (row n1==0 only).
__global__ void prep_rowbias(const float* __restrict__ br, const float* __restrict__ bi,
                             float* __restrict__ RB) {
    int idx = blockIdx.x * 256 + threadIdx.x;       // 131072 = 4*256*128
    int l = idx >> 15;
    int c = (idx >> 7) & 255;
    int o = idx & 127;
    float v;
    if (c == 0) {
        v = br[(l << 7) + o];
    } else {
        float s = 0.0f;
        for (int k = 1; k < 128; k++) {
            int m = (k * c) & 255;
            s += sinf(0.024543692952156857f * (float)m);  // pi/128
        }
        v = -bi[(l << 7) + o] * s * 0.0078125f;
    }
    RB[idx] = v;
}

// Abuf layout (ushort): [sd2][kt4][half2][pair32][qj(APAD)]; qj = k&31.
#define APAD 40
#define A_IDX(sd, kt, hf, pair, qj) ((((((sd)*4 + (kt))*2 + (hf))*32 + (pair))*APAD) + (qj))
// Wbf chunk-relative index: [mat2][half2][quad4][col128][j8]
#define W_IDX(m2, hf, quad, col) (((((m2)*2 + (hf))*4 + (quad))*128 + (col))*8)

// K-loop core: U += E'^T s (3-term split), V += F'^T d. Frags: A from LDS, B from L2.
__device__ __forceinline__ void layer_core(const unsigned short* Abuf,
        const unsigned short* __restrict__ Wl, int wv, int l15, int quad,
        f4v U[2][2], f4v V[2][2])
{
    #pragma unroll
    for (int mt = 0; mt < 2; mt++)
        #pragma unroll
        for (int nt = 0; nt < 2; nt++) {
            U[mt][nt] = (f4v){0.f, 0.f, 0.f, 0.f};
            V[mt][nt] = (f4v){0.f, 0.f, 0.f, 0.f};
        }
    #pragma unroll
    for (int kc = 0; kc < 4; kc++) {
        s8v bf[2][2][2];
        #pragma unroll
        for (int m2 = 0; m2 < 2; m2++)
            #pragma unroll
            for (int hf = 0; hf < 2; hf++)
                #pragma unroll
                for (int nt = 0; nt < 2; nt++)
                    bf[m2][hf][nt] = *(const s8v*)&Wl[kc * 16384 +
                            W_IDX(m2, hf, quad, wv * 32 + nt * 16 + l15)];
        s8v a[2][2][2];
        #pragma unroll
        for (int sd = 0; sd < 2; sd++)
            #pragma unroll
            for (int hf = 0; hf < 2; hf++)
                #pragma unroll
                for (int mt = 0; mt < 2; mt++)
                    a[sd][hf][mt] = *(const s8v*)&Abuf[A_IDX(sd, kc, hf, mt * 16 + l15, quad * 8)];
        #pragma unroll
        for (int mt = 0; mt < 2; mt++)
            #pragma unroll
            for (int nt = 0; nt < 2; nt++) {
                U[mt][nt] = __builtin_amdgcn_mfma_f32_16x16x32_bf16(a[0][0][mt], bf[0][0][nt], U[mt][nt], 0, 0, 0);
                V[mt][nt] = __builtin_amdgcn_mfma_f32_16x16x32_bf16(a[1][0][mt], bf[1][0][nt], V[mt][nt], 0, 0, 0);
                U[mt][nt] = __builtin_amdgcn_mfma_f32_16x16x32_bf16(a[0][0][mt], bf[0][1][nt], U[mt][nt], 0, 0, 0);
                V[mt][nt] = __builtin_amdgcn_mfma_f32_16x16x32_bf16(a[1][0][mt], bf[1][1][nt], V[mt][nt], 0, 0, 0);
                U[mt][nt] = __builtin_amdgcn_mfma_f32_16x16x32_bf16(a[0][1][mt], bf[0][0][nt], U[mt][nt], 0, 0, 0);
                V[mt][nt] = __builtin_amdgcn_mfma_f32_16x16x32_bf16(a[1][1][mt], bf[1][0][nt], V[mt][nt], 0, 0, 0);
            }
    }
}

__global__ __launch_bounds__(256, 3) void fno_fused(
        const float* __restrict__ x,
        const float* __restrict__ w_in, const float* __restrict__ b_in,
        const unsigned short* __restrict__ Wbf,
        const float* __restrict__ W2,
        const float* __restrict__ RB,
        const float* __restrict__ cb,
        const float* __restrict__ wo, const float* __restrict__ bo,
        float* __restrict__ out)
{
    __shared__ unsigned short Abuf[2 * 4 * 2 * 32 * APAD];   // 40 KB

    int bid = blockIdx.x;
    int tid = threadIdx.x;

    if (bid >= 4096) {
        // --- special: self-paired pixels (b,0,0) and (b,128,0), fp32 path, fully fused ---
        float* Hs = (float*)Abuf;
        int b2 = bid - 4096;
        int o = tid & 127;
        int rowp = (tid < 128) ? 0 : 128;
        float acc = b_in[o];
        #pragma unroll
        for (int c = 0; c < 3; c++)
            acc = fmaf(x[((b2 * 3 + c) << 16) + (rowp << 8)], w_in[c * 128 + o], acc);
        float hval = gelu_f(acc);
        for (int l = 0; l < 4; l++) {
            __syncthreads();
            Hs[tid] = hval;
            __syncthreads();
            const float* W2l = W2 + l * 32768;          // E' (which=0) plane
            const float* hb = Hs + ((tid < 128) ? 0 : 128);
            float a2 = 0.0f;
            for (int i = 0; i < 128; i++) a2 = fmaf(W2l[(i << 7) + o], hb[i], a2);
            a2 = 2.0f * a2 + cb[l * 128 + o];
            if (tid < 128) a2 += RB[l * 32768 + o];     // row 0, col 0
            hval = gelu_f(a2);
        }
        __syncthreads();
        Hs[tid] = hval * wo[o];
        __syncthreads();
        #pragma unroll
        for (int off = 64; off >= 1; off >>= 1) {
            if ((tid & 127) < off) Hs[tid] += Hs[tid + off];
            __syncthreads();
        }
        if ((tid & 127) == 0) out[(b2 << 16) + (rowp << 8)] = gelu_f(Hs[tid] + bo[0]);
        return;
    }

    int b = bid >> 10;
    int rem = bid & 1023;
    int r, c0, rq;
    bool rowzero;
    if (rem < 1016) {
        r = 1 + (rem >> 3);
        c0 = (rem & 7) << 5;
        rq = 256 - r;
        rowzero = false;
    } else {
        int idx2 = rem - 1016;
        r = (idx2 < 4) ? 0 : 128;
        c0 = 1 + ((idx2 & 3) << 5);
        rq = r;
        rowzero = (r == 0);
    }

    // ---- lin_in + stage A: h = gelu(x*Win+bin); s/d split-bf16 into Abuf ----
    {
        int j2 = tid >> 3;                  // pair 0..31
        int seg = tid & 7;                  // 16-ch segment
        int ch0 = seg << 4;
        int cp = c0 + j2;
        int cq = (256 - cp) & 255;
        float xp[3], xq[3];
        #pragma unroll
        for (int c = 0; c < 3; c++) {
            xp[c] = x[((b * 3 + c) << 16) + (r << 8) + cp];
            xq[c] = x[((b * 3 + c) << 16) + (rq << 8) + cq];
        }
        int kt = seg >> 1;
        int qjb = (seg & 1) << 4;
        #pragma unroll
        for (int e = 0; e < 2; e++) {
            alignas(16) unsigned short sh[8], sl[8], dh[8], dl[8];
            #pragma unroll
            for (int jj = 0; jj < 8; jj++) {
                int d = ch0 + e * 8 + jj;
                float ap = b_in[d], aq = b_in[d];
                #pragma unroll
                for (int c = 0; c < 3; c++) {
                    float w = w_in[c * 128 + d];
                    ap = fmaf(xp[c], w, ap);
                    aq = fmaf(xq[c], w, aq);
                }
                float hp = gelu_f(ap), hq = gelu_f(aq);
                float s = hp + hq, dd = hp - hq;
                unsigned short shi = bf16_rne(s);
                unsigned short dhi = bf16_rne(dd);
                sh[jj] = shi; sl[jj] = bf16_rne(s - bf16_tof(shi));
                dh[jj] = dhi; dl[jj] = bf16_rne(dd - bf16_tof(dhi));
            }
            int qj = qjb + e * 8;
            *(s8v*)&Abuf[A_IDX(0, kt, 0, j2, qj)] = *(const s8v*)sh;
            *(s8v*)&Abuf[A_IDX(0, kt, 1, j2, qj)] = *(const s8v*)sl;
            *(s8v*)&Abuf[A_IDX(1, kt, 0, j2, qj)] = *(const s8v*)dh;
            *(s8v*)&Abuf[A_IDX(1, kt, 1, j2, qj)] = *(const s8v*)dl;
        }
    }

    int lane = tid & 63;
    int wv = tid >> 6;                      // wave -> 32-col (out-ch) strip
    int l15 = lane & 15;
    int quad = lane >> 4;
    int och0 = wv * 32 + l15;               // nt=0 out-ch
    int och1 = och0 + 16;                   // nt=1 out-ch

    // ---- layers 0..2: GEMM + epilogue + restage ----
    for (int l = 0; l < 3; l++) {
        __syncthreads();                    // Abuf writes visible
        f4v U[2][2], V[2][2];
        layer_core(Abuf, Wbf + l * 65536, wv, l15, quad, U, V);
        __syncthreads();                    // all Abuf reads done before restage

        const float* RBl = RB + l * 32768;
        #pragma unroll
        for (int mt = 0; mt < 2; mt++)
            #pragma unroll
            for (int nt = 0; nt < 2; nt++) {
                int och = nt ? och1 : och0;
                float cbv = cb[l * 128 + och];
                #pragma unroll
                for (int rg = 0; rg < 4; rg++) {
                    int pair = mt * 16 + quad * 4 + rg;
                    int colp = c0 + pair;
                    int colq = (256 - colp) & 255;
                    float u = U[mt][nt][rg], v = V[mt][nt][rg];
                    float bp = u + v + cbv;
                    float bq = u - v + cbv;
                    if (rowzero) {
                        bp += RBl[(colp << 7) + och];
                        bq += RBl[(colq << 7) + och];
                    }
                    float hp = gelu_f(bp), hq = gelu_f(bq);
                    // restage for next layer: k = och -> kt=wv, qj = nt*16+l15
                    float s = hp + hq, dd = hp - hq;
                    unsigned short shi = bf16_rne(s);
                    unsigned short dhi = bf16_rne(dd);
                    int qj = nt * 16 + l15;
                    Abuf[A_IDX(0, wv, 0, pair, qj)] = shi;
                    Abuf[A_IDX(0, wv, 1, pair, qj)] = bf16_rne(s - bf16_tof(shi));
                    Abuf[A_IDX(1, wv, 0, pair, qj)] = dhi;
                    Abuf[A_IDX(1, wv, 1, pair, qj)] = bf16_rne(dd - bf16_tof(dhi));
                }
            }
    }

    // ---- layer 3 (peeled): GEMM + epilogue -> lin_out partials (pp/pq live only here) ----
    float pp[8], pq[8];                     // idx = mt*4+rg
    {
        __syncthreads();
        f4v U[2][2], V[2][2];
        layer_core(Abuf, Wbf + 3 * 65536, wv, l15, quad, U, V);
        __syncthreads();                    // all Abuf reads done (Pb reuse below)

        float wo0 = wo[och0], wo1 = wo[och1];
        const float* RBl = RB + 3 * 32768;
        #pragma unroll
        for (int i = 0; i < 8; i++) { pp[i] = 0.0f; pq[i] = 0.0f; }
        #pragma unroll
        for (int mt = 0; mt < 2; mt++)
            #pragma unroll
            for (int nt = 0; nt < 2; nt++) {
                int och = nt ? och1 : och0;
                float cbv = cb[3 * 128 + och];
                float w = nt ? wo1 : wo0;
                #pragma unroll
                for (int rg = 0; rg < 4; rg++) {
                    int pair = mt * 16 + quad * 4 + rg;
                    int colp = c0 + pair;
                    int colq = (256 - colp) & 255;
                    float u = U[mt][nt][rg], v = V[mt][nt][rg];
                    float bp = u + v + cbv;
                    float bq = u - v + cbv;
                    if (rowzero) {
                        bp += RBl[(colp << 7) + och];
                        bq += RBl[(colq << 7) + och];
                    }
                    pp[mt * 4 + rg] = fmaf(gelu_f(bp), w, pp[mt * 4 + rg]);
                    pq[mt * 4 + rg] = fmaf(gelu_f(bq), w, pq[mt * 4 + rg]);
                }
            }
    }

    // ---- lin_out: reduce partials over l15 (16 lanes) then across waves via LDS ----
    #pragma unroll
    for (int i = 0; i < 8; i++) {
        #pragma unroll
        for (int m = 1; m <= 8; m <<= 1) {
            pp[i] += __shfl_xor(pp[i], m, 64);
            pq[i] += __shfl_xor(pq[i], m, 64);
        }
    }
    float* Pb = (float*)Abuf;               // [2][32 pairs][4 wv]
    if (l15 == 0) {
        #pragma unroll
        for (int mt = 0; mt < 2; mt++)
            #pragma unroll
            for (int rg = 0; rg < 4; rg++) {
                int pair = mt * 16 + quad * 4 + rg;
                Pb[(pair << 2) + wv]        = pp[mt * 4 + rg];
                Pb[128 + (pair << 2) + wv]  = pq[mt * 4 + rg];
            }
    }
    __syncthreads();
    if (tid < 64) {
        int pqsel = tid >> 5;
        int pair = tid & 31;
        const float* pb = Pb + pqsel * 128 + (pair << 2);
        float ssum = pb[0] + pb[1] + pb[2] + pb[3] + bo[0];
        int colp = c0 + pair;
        int col = pqsel ? ((256 - colp) & 255) : colp;
        int row = pqsel ? rq : r;
        out[(b << 16) + (row << 8) + col] = gelu_f(ssum);
    }
}

extern "C" void kernel_launch(void* const* d_in, const int* in_sizes, int n_in,
                              void* d_out, int out_size, void* d_ws, size_t ws_size,
                              hipStream_t stream) {
    const float* x         = (const float*)d_in[0];
    const float* lin_in_w  = (const float*)d_in[1];
    const float* lin_in_b  = (const float*)d_in[2];
    const float* wr        = (const float*)d_in[3];
    const float* wi        = (const float*)d_in[4];
    const float* br        = (const float*)d_in[5];
    const float* bi        = (const float*)d_in[6];
    const float* cw        = (const float*)d_in[7];
    const float* cb        = (const float*)d_in[8];
    const float* lin_out_w = (const float*)d_in[9];
    const float* lin_out_b = (const float*)d_in[10];
    float* out = (float*)d_out;

    size_t need = (size_t)(W2_FLOATS + RB_FLOATS) * sizeof(float)
                + (size_t)WBF_USHORTS * sizeof(unsigned short);
    if (ws_size < need) return;
    float* ws = (float*)d_ws;
    float* W2 = ws;
    float* RB = W2 + W2_FLOATS;
    unsigned short* Wbf = (unsigned short*)(RB + RB_FLOATS);

    prep_weights<<<512, 256, 0, stream>>>(wr, wi, cw, W2);
    prep_weights_bf16<<<512, 256, 0, stream>>>(wr, wi, cw, Wbf);
    prep_rowbias<<<512, 256, 0, stream>>>(br, bi, RB);
    fno_fused<<<4100, 256, 0, stream>>>(x, lin_in_w, lin_in_b, Wbf, W2, RB,
                                        cb, lin_out_w, lin_out_b, out);
}

// Round 6
// 325.584 us; speedup vs baseline: 1.2900x; 1.2900x over previous
//
#include <hip/hip_runtime.h>

// FNO2d fully fused: lin_in -> 4 spectral+conv layers -> lin_out in ONE kernel.
// Full-mode spectral conv == pair-local mixing (p paired with -p mod 256).
// R6: 512-thread blocks (8 waves, N=16 strip/wave) to halve per-thread regs ->
//     2 blocks/CU at launch_bounds(512,4) without spills; branch-free gelu.
#define W2_FLOATS   131072     // 4 layers * 2 (E,F) * 128*128  (fp32, special path uses E')
#define RB_FLOATS   131072     // 4 layers * 256 cols * 128 ch
#define WBF_USHORTS 262144     // 4 layers * 4 chunks * 16384 (split-bf16 B-operand layout)

typedef short s8v __attribute__((ext_vector_type(8)));   // 8 bf16 (4 VGPRs)
typedef float f4v __attribute__((ext_vector_type(4)));   // MFMA acc

// Branch-free gelu: 0.5x(1+erf(x/sqrt2)) via A&S 7.1.26 (|err_erf|<1.5e-7).
__device__ __forceinline__ float gelu_f(float x) {
    float ax = fabsf(x);
    float z  = ax * 0.7071067811865476f;
    float t  = __builtin_amdgcn_rcpf(fmaf(0.3275911f, z, 1.0f));
    float p  = t * fmaf(t, fmaf(t, fmaf(t, fmaf(t, 1.061405429f, -1.453152027f),
                                        1.421413741f), -0.284496736f), 0.254829592f);
    float e  = __expf(-z * z);
    float hx = 0.5f * ax;
    return fmaf(0.5f, x, hx) - hx * p * e;
}
__device__ __forceinline__ unsigned short bf16_rne(float v) {
    unsigned u = __float_as_uint(v);
    unsigned r = u + 0x7FFFu + ((u >> 16) & 1u);
    return (unsigned short)(r >> 16);
}
__device__ __forceinline__ float bf16_tof(unsigned short x) {
    return __uint_as_float(((unsigned)x) << 16);
}

// W2[l][which][i][o] = 0.5*(cw[l][o][i] + (which? wi : wr)[l][i][o])  (fp32, special path)
__global__ void prep_weights(const float* __restrict__ wr, const float* __restrict__ wi,
                             const float* __restrict__ cw, float* __restrict__ W2) {
    int idx = blockIdx.x * 256 + threadIdx.x;       // 131072
    int l = idx >> 15;
    int which = (idx >> 14) & 1;
    int i = (idx >> 7) & 127;
    int o = idx & 127;
    const float* w = which ? wi : wr;
    W2[idx] = 0.5f * (cw[(l << 14) + (o << 7) + i] + w[(l << 14) + (i << 7) + o]);
}

// Split-bf16 weights in B-operand layout.
// Wbf[l][kc][mat][half][quad][col][j]; k = kc*32 + quad*8 + j (input ch), col = out ch.
__global__ void prep_weights_bf16(const float* __restrict__ wr, const float* __restrict__ wi,
                                  const float* __restrict__ cw, unsigned short* __restrict__ Wbf) {
    int t = blockIdx.x * 256 + threadIdx.x;         // 131072 = 4*4*2*4*128*8
    int j    = t & 7;
    int col  = (t >> 3) & 127;
    int quad = (t >> 10) & 3;
    int m2   = (t >> 12) & 1;
    int kc   = (t >> 13) & 3;
    int l    = t >> 15;
    int k = kc * 32 + quad * 8 + j;
    const float* w = m2 ? wi : wr;
    float v = 0.5f * (cw[(l << 14) + (col << 7) + k] + w[(l << 14) + (k << 7) + col]);
    unsigned short hi = bf16_rne(v);
    unsigned short lo = bf16_rne(v - bf16_tof(hi));
    int base = (l * 4 + kc) * 16384;
    int idx_hi = base + (((m2 * 2 + 0) * 4 + quad) * 128 + col) * 8 + j;
    int idx_lo = base + (((m2 * 2 + 1) * 4 + quad) * 128 + col) * 8 + j;
    Wbf[idx_hi] = hi;
    Wbf[idx_lo] = lo;
}

// RB[l][c][o]: spatial map of the per-frequency constant bias (row n1==0 only).
__global__ void prep_rowbias(const float* __restrict__ br, const float* __restrict__ bi,
                             float* __restrict__ RB) {
    int idx = blockIdx.x * 256 + threadIdx.x;       // 131072 = 4*256*128
    int l = idx >> 15;
    int c = (idx >> 7) & 255;
    int o = idx & 127;
    float v;
    if (c == 0) {
        v = br[(l << 7) + o];
    } else {
        float s = 0.0f;
        for (int k = 1; k < 128; k++) {
            int m = (k * c) & 255;
            s += sinf(0.024543692952156857f * (float)m);  // pi/128
        }
        v = -bi[(l << 7) + o] * s * 0.0078125f;
    }
    RB[idx] = v;
}

// Abuf layout (ushort): [sd2][kt4][half2][pair32][qj(APAD)]; qj = k&31.
#define APAD 40
#define A_IDX(sd, kt, hf, pair, qj) ((((((sd)*4 + (kt))*2 + (hf))*32 + (pair))*APAD) + (qj))
// Wbf chunk-relative index: [mat2][half2][quad4][col128][j8]
#define W_IDX(m2, hf, quad, col) (((((m2)*2 + (hf))*4 + (quad))*128 + (col))*8)

// K-loop core (per wave: M=32 pairs x N=16 och). U += E'^T s, V += F'^T d (3-term split).
__device__ __forceinline__ void layer_core(const unsigned short* Abuf,
        const unsigned short* __restrict__ Wl, int wv, int l15, int quad,
        f4v U[2], f4v V[2])
{
    U[0] = (f4v){0.f, 0.f, 0.f, 0.f}; U[1] = (f4v){0.f, 0.f, 0.f, 0.f};
    V[0] = (f4v){0.f, 0.f, 0.f, 0.f}; V[1] = (f4v){0.f, 0.f, 0.f, 0.f};
    #pragma unroll
    for (int kc = 0; kc < 4; kc++) {
        s8v bf[2][2];                       // [mat][half], N=16 strip
        #pragma unroll
        for (int m2 = 0; m2 < 2; m2++)
            #pragma unroll
            for (int hf = 0; hf < 2; hf++)
                bf[m2][hf] = *(const s8v*)&Wl[kc * 16384 +
                        W_IDX(m2, hf, quad, wv * 16 + l15)];
        s8v a[2][2][2];                     // [sd][half][mt]
        #pragma unroll
        for (int sd = 0; sd < 2; sd++)
            #pragma unroll
            for (int hf = 0; hf < 2; hf++)
                #pragma unroll
                for (int mt = 0; mt < 2; mt++)
                    a[sd][hf][mt] = *(const s8v*)&Abuf[A_IDX(sd, kc, hf, mt * 16 + l15, quad * 8)];
        #pragma unroll
        for (int mt = 0; mt < 2; mt++) {
            U[mt] = __builtin_amdgcn_mfma_f32_16x16x32_bf16(a[0][0][mt], bf[0][0], U[mt], 0, 0, 0);
            V[mt] = __builtin_amdgcn_mfma_f32_16x16x32_bf16(a[1][0][mt], bf[1][0], V[mt], 0, 0, 0);
            U[mt] = __builtin_amdgcn_mfma_f32_16x16x32_bf16(a[0][0][mt], bf[0][1], U[mt], 0, 0, 0);
            V[mt] = __builtin_amdgcn_mfma_f32_16x16x32_bf16(a[1][0][mt], bf[1][1], V[mt], 0, 0, 0);
            U[mt] = __builtin_amdgcn_mfma_f32_16x16x32_bf16(a[0][1][mt], bf[0][0], U[mt], 0, 0, 0);
            V[mt] = __builtin_amdgcn_mfma_f32_16x16x32_bf16(a[1][1][mt], bf[1][0], V[mt], 0, 0, 0);
        }
    }
}

__global__ __launch_bounds__(512, 4) void fno_fused(
        const float* __restrict__ x,
        const float* __restrict__ w_in, const float* __restrict__ b_in,
        const unsigned short* __restrict__ Wbf,
        const float* __restrict__ W2,
        const float* __restrict__ RB,
        const float* __restrict__ cb,
        const float* __restrict__ wo, const float* __restrict__ bo,
        float* __restrict__ out)
{
    __shared__ unsigned short Abuf[2 * 4 * 2 * 32 * APAD];   // 40 KB

    int bid = blockIdx.x;
    int tid = threadIdx.x;

    if (bid >= 4096) {
        // --- special: self-paired pixels (b,0,0) and (b,128,0), fp32 path ---
        // Only tid<256 does work; all threads hit the barriers.
        float* Hs = (float*)Abuf;
        int b2 = bid - 4096;
        int o = tid & 127;
        int rowp = (tid < 128) ? 0 : 128;
        float hval = 0.0f;
        if (tid < 256) {
            float acc = b_in[o];
            #pragma unroll
            for (int c = 0; c < 3; c++)
                acc = fmaf(x[((b2 * 3 + c) << 16) + (rowp << 8)], w_in[c * 128 + o], acc);
            hval = gelu_f(acc);
        }
        for (int l = 0; l < 4; l++) {
            __syncthreads();
            if (tid < 256) Hs[tid] = hval;
            __syncthreads();
            if (tid < 256) {
                const float* W2l = W2 + l * 32768;          // E' (which=0) plane
                const float* hb = Hs + ((tid < 128) ? 0 : 128);
                float a2 = 0.0f;
                for (int i = 0; i < 128; i++) a2 = fmaf(W2l[(i << 7) + o], hb[i], a2);
                a2 = 2.0f * a2 + cb[l * 128 + o];
                if (tid < 128) a2 += RB[l * 32768 + o];     // row 0, col 0
                hval = gelu_f(a2);
            }
        }
        __syncthreads();
        if (tid < 256) Hs[tid] = hval * wo[o];
        __syncthreads();
        #pragma unroll
        for (int off = 64; off >= 1; off >>= 1) {
            if (tid < 256 && (tid & 127) < off) Hs[tid] += Hs[tid + off];
            __syncthreads();
        }
        if (tid < 256 && (tid & 127) == 0) out[(b2 << 16) + (rowp << 8)] = gelu_f(Hs[tid] + bo[0]);
        return;
    }

    int b = bid >> 10;
    int rem = bid & 1023;
    int r, c0, rq;
    bool rowzero;
    if (rem < 1016) {
        r = 1 + (rem >> 3);
        c0 = (rem & 7) << 5;
        rq = 256 - r;
        rowzero = false;
    } else {
        int idx2 = rem - 1016;
        r = (idx2 < 4) ? 0 : 128;
        c0 = 1 + ((idx2 & 3) << 5);
        rq = r;
        rowzero = (r == 0);
    }

    // ---- lin_in + stage A: h = gelu(x*Win+bin); s/d split-bf16 into Abuf ----
    {
        int j2 = tid >> 4;                  // pair 0..31
        int seg = tid & 15;                 // 8-ch segment
        int ch0 = seg << 3;
        int cp = c0 + j2;
        int cq = (256 - cp) & 255;
        float xp[3], xq[3];
        #pragma unroll
        for (int c = 0; c < 3; c++) {
            xp[c] = x[((b * 3 + c) << 16) + (r << 8) + cp];
            xq[c] = x[((b * 3 + c) << 16) + (rq << 8) + cq];
        }
        int kt = seg >> 2;
        int qj = (seg & 3) << 3;
        alignas(16) unsigned short sh[8], sl[8], dh[8], dl[8];
        #pragma unroll
        for (int jj = 0; jj < 8; jj++) {
            int d = ch0 + jj;
            float ap = b_in[d], aq = ap;
            #pragma unroll
            for (int c = 0; c < 3; c++) {
                float w = w_in[c * 128 + d];
                ap = fmaf(xp[c], w, ap);
                aq = fmaf(xq[c], w, aq);
            }
            float hp = gelu_f(ap), hq = gelu_f(aq);
            float s = hp + hq, dd = hp - hq;
            unsigned short shi = bf16_rne(s);
            unsigned short dhi = bf16_rne(dd);
            sh[jj] = shi; sl[jj] = bf16_rne(s - bf16_tof(shi));
            dh[jj] = dhi; dl[jj] = bf16_rne(dd - bf16_tof(dhi));
        }
        *(s8v*)&Abuf[A_IDX(0, kt, 0, j2, qj)] = *(const s8v*)sh;
        *(s8v*)&Abuf[A_IDX(0, kt, 1, j2, qj)] = *(const s8v*)sl;
        *(s8v*)&Abuf[A_IDX(1, kt, 0, j2, qj)] = *(const s8v*)dh;
        *(s8v*)&Abuf[A_IDX(1, kt, 1, j2, qj)] = *(const s8v*)dl;
    }

    int lane = tid & 63;
    int wv = tid >> 6;                      // wave -> 16-och strip
    int l15 = lane & 15;
    int quad = lane >> 4;
    int och = wv * 16 + l15;                // this thread's out-channel
    int rkt = wv >> 1;                      // restage kt
    int rqj = ((wv & 1) << 4) + l15;        // restage qj

    // ---- layers 0..2: GEMM + epilogue + restage ----
    for (int l = 0; l < 3; l++) {
        __syncthreads();                    // Abuf writes visible
        f4v U[2], V[2];
        layer_core(Abuf, Wbf + l * 65536, wv, l15, quad, U, V);
        __syncthreads();                    // all Abuf reads done before restage

        const float* RBl = RB + l * 32768;
        float cbv = cb[l * 128 + och];
        #pragma unroll
        for (int mt = 0; mt < 2; mt++)
            #pragma unroll
            for (int rg = 0; rg < 4; rg++) {
                int pair = mt * 16 + quad * 4 + rg;
                int colp = c0 + pair;
                int colq = (256 - colp) & 255;
                float u = U[mt][rg], v = V[mt][rg];
                float bp = u + v + cbv;
                float bq = u - v + cbv;
                if (rowzero) {
                    bp += RBl[(colp << 7) + och];
                    bq += RBl[(colq << 7) + och];
                }
                float hp = gelu_f(bp), hq = gelu_f(bq);
                float s = hp + hq, dd = hp - hq;
                unsigned short shi = bf16_rne(s);
                unsigned short dhi = bf16_rne(dd);
                Abuf[A_IDX(0, rkt, 0, pair, rqj)] = shi;
                Abuf[A_IDX(0, rkt, 1, pair, rqj)] = bf16_rne(s - bf16_tof(shi));
                Abuf[A_IDX(1, rkt, 0, pair, rqj)] = dhi;
                Abuf[A_IDX(1, rkt, 1, pair, rqj)] = bf16_rne(dd - bf16_tof(dhi));
            }
    }

    // ---- layer 3 (peeled): GEMM + epilogue -> lin_out partials ----
    float pp[8], pq[8];                     // idx = mt*4+rg
    {
        __syncthreads();
        f4v U[2], V[2];
        layer_core(Abuf, Wbf + 3 * 65536, wv, l15, quad, U, V);
        __syncthreads();                    // all Abuf reads done (Pb reuse below)

        float wov = wo[och];
        const float* RBl = RB + 3 * 32768;
        float cbv = cb[3 * 128 + och];
        #pragma unroll
        for (int mt = 0; mt < 2; mt++)
            #pragma unroll
            for (int rg = 0; rg < 4; rg++) {
                int pair = mt * 16 + quad * 4 + rg;
                int colp = c0 + pair;
                int colq = (256 - colp) & 255;
                float u = U[mt][rg], v = V[mt][rg];
                float bp = u + v + cbv;
                float bq = u - v + cbv;
                if (rowzero) {
                    bp += RBl[(colp << 7) + och];
                    bq += RBl[(colq << 7) + och];
                }
                pp[mt * 4 + rg] = gelu_f(bp) * wov;
                pq[mt * 4 + rg] = gelu_f(bq) * wov;
            }
    }

    // ---- lin_out: reduce over l15 (16 lanes) then across 8 waves via LDS ----
    #pragma unroll
    for (int i = 0; i < 8; i++) {
        #pragma unroll
        for (int m = 1; m <= 8; m <<= 1) {
            pp[i] += __shfl_xor(pp[i], m, 64);
            pq[i] += __shfl_xor(pq[i], m, 64);
        }
    }
    float* Pb = (float*)Abuf;               // [2][32 pairs][8 wv]
    if (l15 == 0) {
        #pragma unroll
        for (int mt = 0; mt < 2; mt++)
            #pragma unroll
            for (int rg = 0; rg < 4; rg++) {
                int pair = mt * 16 + quad * 4 + rg;
                Pb[(pair << 3) + wv]        = pp[mt * 4 + rg];
                Pb[256 + (pair << 3) + wv]  = pq[mt * 4 + rg];
            }
    }
    __syncthreads();
    if (tid < 64) {
        int pqsel = tid >> 5;
        int pair = tid & 31;
        const float* pb = Pb + pqsel * 256 + (pair << 3);
        float ssum = ((pb[0] + pb[1]) + (pb[2] + pb[3])) +
                     ((pb[4] + pb[5]) + (pb[6] + pb[7])) + bo[0];
        int colp = c0 + pair;
        int col = pqsel ? ((256 - colp) & 255) : colp;
        int row = pqsel ? rq : r;
        out[(b << 16) + (row << 8) + col] = gelu_f(ssum);
    }
}

extern "C" void kernel_launch(void* const* d_in, const int* in_sizes, int n_in,
                              void* d_out, int out_size, void* d_ws, size_t ws_size,
                              hipStream_t stream) {
    const float* x         = (const float*)d_in[0];
    const float* lin_in_w  = (const float*)d_in[1];
    const float* lin_in_b  = (const float*)d_in[2];
    const float* wr        = (const float*)d_in[3];
    const float* wi        = (const float*)d_in[4];
    const float* br        = (const float*)d_in[5];
    const float* bi        = (const float*)d_in[6];
    const float* cw        = (const float*)d_in[7];
    const float* cb        = (const float*)d_in[8];
    const float* lin_out_w = (const float*)d_in[9];
    const float* lin_out_b = (const float*)d_in[10];
    float* out = (float*)d_out;

    size_t need = (size_t)(W2_FLOATS + RB_FLOATS) * sizeof(float)
                + (size_t)WBF_USHORTS * sizeof(unsigned short);
    if (ws_size < need) return;
    float* ws = (float*)d_ws;
    float* W2 = ws;
    float* RB = W2 + W2_FLOATS;
    unsigned short* Wbf = (unsigned short*)(RB + RB_FLOATS);

    prep_weights<<<512, 256, 0, stream>>>(wr, wi, cw, W2);
    prep_weights_bf16<<<512, 256, 0, stream>>>(wr, wi, cw, Wbf);
    prep_rowbias<<<512, 256, 0, stream>>>(br, bi, RB);
    fno_fused<<<4100, 512, 0, stream>>>(x, lin_in_w, lin_in_b, Wbf, W2, RB,
                                        cb, lin_out_w, lin_out_b, out);
}

// Round 7
// 282.996 us; speedup vs baseline: 1.4841x; 1.1505x over previous
//
#include <hip/hip_runtime.h>

// FNO2d fully fused: lin_in -> 4 spectral+conv layers -> lin_out in ONE kernel.
// Full-mode spectral conv == pair-local mixing (p paired with -p mod 256).
// R7: kill register spill (R6: 263 MB scratch writebacks). layer_core now does
//     U-pass (sd=0,E') then V-pass (sd=1,F') per kc: peak live frags 48->24 regs,
//     so true demand fits the (512,4) 128-reg cap with no scratch.
#define W2_FLOATS   131072     // 4 layers * 2 (E,F) * 128*128  (fp32, special path uses E')
#define RB_FLOATS   131072     // 4 layers * 256 cols * 128 ch
#define WBF_USHORTS 262144     // 4 layers * 4 chunks * 16384 (split-bf16 B-operand layout)

typedef short s8v __attribute__((ext_vector_type(8)));   // 8 bf16 (4 VGPRs)
typedef float f4v __attribute__((ext_vector_type(4)));   // MFMA acc

// Branch-free gelu: 0.5x(1+erf(x/sqrt2)) via A&S 7.1.26 (|err_erf|<1.5e-7).
__device__ __forceinline__ float gelu_f(float x) {
    float ax = fabsf(x);
    float z  = ax * 0.7071067811865476f;
    float t  = __builtin_amdgcn_rcpf(fmaf(0.3275911f, z, 1.0f));
    float p  = t * fmaf(t, fmaf(t, fmaf(t, fmaf(t, 1.061405429f, -1.453152027f),
                                        1.421413741f), -0.284496736f), 0.254829592f);
    float e  = __expf(-z * z);
    float hx = 0.5f * ax;
    return fmaf(0.5f, x, hx) - hx * p * e;
}
__device__ __forceinline__ unsigned short bf16_rne(float v) {
    unsigned u = __float_as_uint(v);
    unsigned r = u + 0x7FFFu + ((u >> 16) & 1u);
    return (unsigned short)(r >> 16);
}
__device__ __forceinline__ float bf16_tof(unsigned short x) {
    return __uint_as_float(((unsigned)x) << 16);
}

// W2[l][which][i][o] = 0.5*(cw[l][o][i] + (which? wi : wr)[l][i][o])  (fp32, special path)
__global__ void prep_weights(const float* __restrict__ wr, const float* __restrict__ wi,
                             const float* __restrict__ cw, float* __restrict__ W2) {
    int idx = blockIdx.x * 256 + threadIdx.x;       // 131072
    int l = idx >> 15;
    int which = (idx >> 14) & 1;
    int i = (idx >> 7) & 127;
    int o = idx & 127;
    const float* w = which ? wi : wr;
    W2[idx] = 0.5f * (cw[(l << 14) + (o << 7) + i] + w[(l << 14) + (i << 7) + o]);
}

// Split-bf16 weights in B-operand layout.
// Wbf[l][kc][mat][half][quad][col][j]; k = kc*32 + quad*8 + j (input ch), col = out ch.
__global__ void prep_weights_bf16(const float* __restrict__ wr, const float* __restrict__ wi,
                                  const float* __restrict__ cw, unsigned short* __restrict__ Wbf) {
    int t = blockIdx.x * 256 + threadIdx.x;         // 131072 = 4*4*2*4*128*8
    int j    = t & 7;
    int col  = (t >> 3) & 127;
    int quad = (t >> 10) & 3;
    int m2   = (t >> 12) & 1;
    int kc   = (t >> 13) & 3;
    int l    = t >> 15;
    int k = kc * 32 + quad * 8 + j;
    const float* w = m2 ? wi : wr;
    float v = 0.5f * (cw[(l << 14) + (col << 7) + k] + w[(l << 14) + (k << 7) + col]);
    unsigned short hi = bf16_rne(v);
    unsigned short lo = bf16_rne(v - bf16_tof(hi));
    int base = (l * 4 + kc) * 16384;
    int idx_hi = base + (((m2 * 2 + 0) * 4 + quad) * 128 + col) * 8 + j;
    int idx_lo = base + (((m2 * 2 + 1) * 4 + quad) * 128 + col) * 8 + j;
    Wbf[idx_hi] = hi;
    Wbf[idx_lo] = lo;
}

// RB[l][c][o]: spatial map of the per-frequency constant bias (row n1==0 only).
__global__ void prep_rowbias(const float* __restrict__ br, const float* __restrict__ bi,
                             float* __restrict__ RB) {
    int idx = blockIdx.x * 256 + threadIdx.x;       // 131072 = 4*256*128
    int l = idx >> 15;
    int c = (idx >> 7) & 255;
    int o = idx & 127;
    float v;
    if (c == 0) {
        v = br[(l << 7) + o];
    } else {
        float s = 0.0f;
        for (int k = 1; k < 128; k++) {
            int m = (k * c) & 255;
            s += sinf(0.024543692952156857f * (float)m);  // pi/128
        }
        v = -bi[(l << 7) + o] * s * 0.0078125f;
    }
    RB[idx] = v;
}

// Abuf layout (ushort): [sd2][kt4][half2][pair32][qj(APAD)]; qj = k&31.
#define APAD 40
#define A_IDX(sd, kt, hf, pair, qj) ((((((sd)*4 + (kt))*2 + (hf))*32 + (pair))*APAD) + (qj))
// Wbf chunk-relative index: [mat2][half2][quad4][col128][j8]
#define W_IDX(m2, hf, quad, col) (((((m2)*2 + (hf))*4 + (quad))*128 + (col))*8)

// K-loop core (per wave: M=32 pairs x N=16 och). U += E'^T s, V += F'^T d (3-term split).
// Two half-passes per kc (U then V) to keep peak live fragments at 24 regs.
__device__ __forceinline__ void layer_core(const unsigned short* Abuf,
        const unsigned short* __restrict__ Wl, int wv, int l15, int quad,
        f4v U[2], f4v V[2])
{
    U[0] = (f4v){0.f, 0.f, 0.f, 0.f}; U[1] = (f4v){0.f, 0.f, 0.f, 0.f};
    V[0] = (f4v){0.f, 0.f, 0.f, 0.f}; V[1] = (f4v){0.f, 0.f, 0.f, 0.f};
    #pragma unroll
    for (int kc = 0; kc < 4; kc++) {
        {   // ---- U pass: sd=0 (s rows), E' (m2=0) ----
            s8v b0 = *(const s8v*)&Wl[kc * 16384 + W_IDX(0, 0, quad, wv * 16 + l15)];
            s8v b1 = *(const s8v*)&Wl[kc * 16384 + W_IDX(0, 1, quad, wv * 16 + l15)];
            s8v ah0 = *(const s8v*)&Abuf[A_IDX(0, kc, 0, l15,      quad * 8)];
            s8v ah1 = *(const s8v*)&Abuf[A_IDX(0, kc, 0, 16 + l15, quad * 8)];
            s8v al0 = *(const s8v*)&Abuf[A_IDX(0, kc, 1, l15,      quad * 8)];
            s8v al1 = *(const s8v*)&Abuf[A_IDX(0, kc, 1, 16 + l15, quad * 8)];
            U[0] = __builtin_amdgcn_mfma_f32_16x16x32_bf16(ah0, b0, U[0], 0, 0, 0);
            U[1] = __builtin_amdgcn_mfma_f32_16x16x32_bf16(ah1, b0, U[1], 0, 0, 0);
            U[0] = __builtin_amdgcn_mfma_f32_16x16x32_bf16(ah0, b1, U[0], 0, 0, 0);
            U[1] = __builtin_amdgcn_mfma_f32_16x16x32_bf16(ah1, b1, U[1], 0, 0, 0);
            U[0] = __builtin_amdgcn_mfma_f32_16x16x32_bf16(al0, b0, U[0], 0, 0, 0);
            U[1] = __builtin_amdgcn_mfma_f32_16x16x32_bf16(al1, b0, U[1], 0, 0, 0);
        }
        {   // ---- V pass: sd=1 (d rows), F' (m2=1) ----
            s8v b0 = *(const s8v*)&Wl[kc * 16384 + W_IDX(1, 0, quad, wv * 16 + l15)];
            s8v b1 = *(const s8v*)&Wl[kc * 16384 + W_IDX(1, 1, quad, wv * 16 + l15)];
            s8v ah0 = *(const s8v*)&Abuf[A_IDX(1, kc, 0, l15,      quad * 8)];
            s8v ah1 = *(const s8v*)&Abuf[A_IDX(1, kc, 0, 16 + l15, quad * 8)];
            s8v al0 = *(const s8v*)&Abuf[A_IDX(1, kc, 1, l15,      quad * 8)];
            s8v al1 = *(const s8v*)&Abuf[A_IDX(1, kc, 1, 16 + l15, quad * 8)];
            V[0] = __builtin_amdgcn_mfma_f32_16x16x32_bf16(ah0, b0, V[0], 0, 0, 0);
            V[1] = __builtin_amdgcn_mfma_f32_16x16x32_bf16(ah1, b0, V[1], 0, 0, 0);
            V[0] = __builtin_amdgcn_mfma_f32_16x16x32_bf16(ah0, b1, V[0], 0, 0, 0);
            V[1] = __builtin_amdgcn_mfma_f32_16x16x32_bf16(ah1, b1, V[1], 0, 0, 0);
            V[0] = __builtin_amdgcn_mfma_f32_16x16x32_bf16(al0, b0, V[0], 0, 0, 0);
            V[1] = __builtin_amdgcn_mfma_f32_16x16x32_bf16(al1, b0, V[1], 0, 0, 0);
        }
    }
}

__global__ __launch_bounds__(512, 4) void fno_fused(
        const float* __restrict__ x,
        const float* __restrict__ w_in, const float* __restrict__ b_in,
        const unsigned short* __restrict__ Wbf,
        const float* __restrict__ W2,
        const float* __restrict__ RB,
        const float* __restrict__ cb,
        const float* __restrict__ wo, const float* __restrict__ bo,
        float* __restrict__ out)
{
    __shared__ unsigned short Abuf[2 * 4 * 2 * 32 * APAD];   // 40 KB

    int bid = blockIdx.x;
    int tid = threadIdx.x;

    if (bid >= 4096) {
        // --- special: self-paired pixels (b,0,0) and (b,128,0), fp32 path ---
        float* Hs = (float*)Abuf;
        int b2 = bid - 4096;
        int o = tid & 127;
        int rowp = (tid < 128) ? 0 : 128;
        float hval = 0.0f;
        if (tid < 256) {
            float acc = b_in[o];
            #pragma unroll
            for (int c = 0; c < 3; c++)
                acc = fmaf(x[((b2 * 3 + c) << 16) + (rowp << 8)], w_in[c * 128 + o], acc);
            hval = gelu_f(acc);
        }
        for (int l = 0; l < 4; l++) {
            __syncthreads();
            if (tid < 256) Hs[tid] = hval;
            __syncthreads();
            if (tid < 256) {
                const float* W2l = W2 + l * 32768;          // E' (which=0) plane
                const float* hb = Hs + ((tid < 128) ? 0 : 128);
                float a2 = 0.0f;
                for (int i = 0; i < 128; i++) a2 = fmaf(W2l[(i << 7) + o], hb[i], a2);
                a2 = 2.0f * a2 + cb[l * 128 + o];
                if (tid < 128) a2 += RB[l * 32768 + o];     // row 0, col 0
                hval = gelu_f(a2);
            }
        }
        __syncthreads();
        if (tid < 256) Hs[tid] = hval * wo[o];
        __syncthreads();
        #pragma unroll
        for (int off = 64; off >= 1; off >>= 1) {
            if (tid < 256 && (tid & 127) < off) Hs[tid] += Hs[tid + off];
            __syncthreads();
        }
        if (tid < 256 && (tid & 127) == 0) out[(b2 << 16) + (rowp << 8)] = gelu_f(Hs[tid] + bo[0]);
        return;
    }

    int b = bid >> 10;
    int rem = bid & 1023;
    int r, c0, rq;
    bool rowzero;
    if (rem < 1016) {
        r = 1 + (rem >> 3);
        c0 = (rem & 7) << 5;
        rq = 256 - r;
        rowzero = false;
    } else {
        int idx2 = rem - 1016;
        r = (idx2 < 4) ? 0 : 128;
        c0 = 1 + ((idx2 & 3) << 5);
        rq = r;
        rowzero = (r == 0);
    }

    // ---- lin_in + stage A: h = gelu(x*Win+bin); s/d split-bf16 into Abuf ----
    {
        int j2 = tid >> 4;                  // pair 0..31
        int seg = tid & 15;                 // 8-ch segment
        int ch0 = seg << 3;
        int cp = c0 + j2;
        int cq = (256 - cp) & 255;
        float xp[3], xq[3];
        #pragma unroll
        for (int c = 0; c < 3; c++) {
            xp[c] = x[((b * 3 + c) << 16) + (r << 8) + cp];
            xq[c] = x[((b * 3 + c) << 16) + (rq << 8) + cq];
        }
        int kt = seg >> 2;
        int qj = (seg & 3) << 3;
        alignas(16) unsigned short sh[8], sl[8], dh[8], dl[8];
        #pragma unroll
        for (int jj = 0; jj < 8; jj++) {
            int d = ch0 + jj;
            float ap = b_in[d], aq = ap;
            #pragma unroll
            for (int c = 0; c < 3; c++) {
                float w = w_in[c * 128 + d];
                ap = fmaf(xp[c], w, ap);
                aq = fmaf(xq[c], w, aq);
            }
            float hp = gelu_f(ap), hq = gelu_f(aq);
            float s = hp + hq, dd = hp - hq;
            unsigned short shi = bf16_rne(s);
            unsigned short dhi = bf16_rne(dd);
            sh[jj] = shi; sl[jj] = bf16_rne(s - bf16_tof(shi));
            dh[jj] = dhi; dl[jj] = bf16_rne(dd - bf16_tof(dhi));
        }
        *(s8v*)&Abuf[A_IDX(0, kt, 0, j2, qj)] = *(const s8v*)sh;
        *(s8v*)&Abuf[A_IDX(0, kt, 1, j2, qj)] = *(const s8v*)sl;
        *(s8v*)&Abuf[A_IDX(1, kt, 0, j2, qj)] = *(const s8v*)dh;
        *(s8v*)&Abuf[A_IDX(1, kt, 1, j2, qj)] = *(const s8v*)dl;
    }

    int lane = tid & 63;
    int wv = tid >> 6;                      // wave -> 16-och strip
    int l15 = lane & 15;
    int quad = lane >> 4;
    int och = wv * 16 + l15;                // this thread's out-channel
    int rkt = wv >> 1;                      // restage kt
    int rqj = ((wv & 1) << 4) + l15;        // restage qj

    // ---- layers 0..2: GEMM + epilogue + restage ----
    for (int l = 0; l < 3; l++) {
        __syncthreads();                    // Abuf writes visible
        f4v U[2], V[2];
        layer_core(Abuf, Wbf + l * 65536, wv, l15, quad, U, V);
        __syncthreads();                    // all Abuf reads done before restage

        const float* RBl = RB + l * 32768;
        float cbv = cb[l * 128 + och];
        #pragma unroll
        for (int mt = 0; mt < 2; mt++)
            #pragma unroll
            for (int rg = 0; rg < 4; rg++) {
                int pair = mt * 16 + quad * 4 + rg;
                int colp = c0 + pair;
                int colq = (256 - colp) & 255;
                float u = U[mt][rg], v = V[mt][rg];
                float bp = u + v + cbv;
                float bq = u - v + cbv;
                if (rowzero) {
                    bp += RBl[(colp << 7) + och];
                    bq += RBl[(colq << 7) + och];
                }
                float hp = gelu_f(bp), hq = gelu_f(bq);
                float s = hp + hq, dd = hp - hq;
                unsigned short shi = bf16_rne(s);
                unsigned short dhi = bf16_rne(dd);
                Abuf[A_IDX(0, rkt, 0, pair, rqj)] = shi;
                Abuf[A_IDX(0, rkt, 1, pair, rqj)] = bf16_rne(s - bf16_tof(shi));
                Abuf[A_IDX(1, rkt, 0, pair, rqj)] = dhi;
                Abuf[A_IDX(1, rkt, 1, pair, rqj)] = bf16_rne(dd - bf16_tof(dhi));
            }
    }

    // ---- layer 3 (peeled): GEMM + epilogue -> lin_out partials ----
    float pp[8], pq[8];                     // idx = mt*4+rg
    {
        __syncthreads();
        f4v U[2], V[2];
        layer_core(Abuf, Wbf + 3 * 65536, wv, l15, quad, U, V);
        __syncthreads();                    // all Abuf reads done (Pb reuse below)

        float wov = wo[och];
        const float* RBl = RB + 3 * 32768;
        float cbv = cb[3 * 128 + och];
        #pragma unroll
        for (int mt = 0; mt < 2; mt++)
            #pragma unroll
            for (int rg = 0; rg < 4; rg++) {
                int pair = mt * 16 + quad * 4 + rg;
                int colp = c0 + pair;
                int colq = (256 - colp) & 255;
                float u = U[mt][rg], v = V[mt][rg];
                float bp = u + v + cbv;
                float bq = u - v + cbv;
                if (rowzero) {
                    bp += RBl[(colp << 7) + och];
                    bq += RBl[(colq << 7) + och];
                }
                pp[mt * 4 + rg] = gelu_f(bp) * wov;
                pq[mt * 4 + rg] = gelu_f(bq) * wov;
            }
    }

    // ---- lin_out: reduce over l15 (16 lanes) then across 8 waves via LDS ----
    #pragma unroll
    for (int i = 0; i < 8; i++) {
        #pragma unroll
        for (int m = 1; m <= 8; m <<= 1) {
            pp[i] += __shfl_xor(pp[i], m, 64);
            pq[i] += __shfl_xor(pq[i], m, 64);
        }
    }
    float* Pb = (float*)Abuf;               // [2][32 pairs][8 wv]
    if (l15 == 0) {
        #pragma unroll
        for (int mt = 0; mt < 2; mt++)
            #pragma unroll
            for (int rg = 0; rg < 4; rg++) {
                int pair = mt * 16 + quad * 4 + rg;
                Pb[(pair << 3) + wv]        = pp[mt * 4 + rg];
                Pb[256 + (pair << 3) + wv]  = pq[mt * 4 + rg];
            }
    }
    __syncthreads();
    if (tid < 64) {
        int pqsel = tid >> 5;
        int pair = tid & 31;
        const float* pb = Pb + pqsel * 256 + (pair << 3);
        float ssum = ((pb[0] + pb[1]) + (pb[2] + pb[3])) +
                     ((pb[4] + pb[5]) + (pb[6] + pb[7])) + bo[0];
        int colp = c0 + pair;
        int col = pqsel ? ((256 - colp) & 255) : colp;
        int row = pqsel ? rq : r;
        out[(b << 16) + (row << 8) + col] = gelu_f(ssum);
    }
}

extern "C" void kernel_launch(void* const* d_in, const int* in_sizes, int n_in,
                              void* d_out, int out_size, void* d_ws, size_t ws_size,
                              hipStream_t stream) {
    const float* x         = (const float*)d_in[0];
    const float* lin_in_w  = (const float*)d_in[1];
    const float* lin_in_b  = (const float*)d_in[2];
    const float* wr        = (const float*)d_in[3];
    const float* wi        = (const float*)d_in[4];
    const float* br        = (const float*)d_in[5];
    const float* bi        = (const float*)d_in[6];
    const float* cw        = (const float*)d_in[7];
    const float* cb        = (const float*)d_in[8];
    const float* lin_out_w = (const float*)d_in[9];
    const float* lin_out_b = (const float*)d_in[10];
    float* out = (float*)d_out;

    size_t need = (size_t)(W2_FLOATS + RB_FLOATS) * sizeof(float)
                + (size_t)WBF_USHORTS * sizeof(unsigned short);
    if (ws_size < need) return;
    float* ws = (float*)d_ws;
    float* W2 = ws;
    float* RB = W2 + W2_FLOATS;
    unsigned short* Wbf = (unsigned short*)(RB + RB_FLOATS);

    prep_weights<<<512, 256, 0, stream>>>(wr, wi, cw, W2);
    prep_weights_bf16<<<512, 256, 0, stream>>>(wr, wi, cw, Wbf);
    prep_rowbias<<<512, 256, 0, stream>>>(br, bi, RB);
    fno_fused<<<4100, 512, 0, stream>>>(x, lin_in_w, lin_in_b, Wbf, W2, RB,
                                        cb, lin_out_w, lin_out_b, out);
}

// Round 8
// 277.751 us; speedup vs baseline: 1.5121x; 1.0189x over previous
//
#include <hip/hip_runtime.h>

// FNO2d fully fused: lin_in -> 4 spectral+conv layers -> lin_out in ONE kernel.
// Full-mode spectral conv == pair-local mixing (p paired with -p mod 256).
// R8: packed-fp32 epilogue math (v_pk_fma_f32 et al. via <2 x float>) +
//     v_cvt_pk_bf16_f32 (guarded) for the hi/lo splits; 3 prep kernels -> 1.
#define W2_FLOATS   131072     // 4 layers * 2 (E,F) * 128*128  (fp32, special path uses E')
#define RB_FLOATS   131072     // 4 layers * 256 cols * 128 ch
#define WBF_USHORTS 262144     // 4 layers * 4 chunks * 16384 (split-bf16 B-operand layout)

typedef short s8v __attribute__((ext_vector_type(8)));   // 8 bf16 (4 VGPRs)
typedef float f4v __attribute__((ext_vector_type(4)));   // MFMA acc
typedef float f2v __attribute__((ext_vector_type(2)));   // packed fp32 (v_pk_*)

#if defined(__has_builtin)
#  if __has_builtin(__builtin_amdgcn_cvt_pk_bf16_f32)
#    define HAVE_PK_BF16 1
#  endif
#endif
#ifndef HAVE_PK_BF16
#  define HAVE_PK_BF16 0
#endif

__device__ __forceinline__ unsigned short bf16_rne(float v) {
    unsigned u = __float_as_uint(v);
    unsigned r = u + 0x7FFFu + ((u >> 16) & 1u);
    return (unsigned short)(r >> 16);
}
__device__ __forceinline__ float bf16_tof(unsigned short x) {
    return __uint_as_float(((unsigned)x) << 16);
}
// pack: low16 = bf16(a), high16 = bf16(b), RNE both paths
__device__ __forceinline__ unsigned pk_bf16(float a, float b) {
#if HAVE_PK_BF16
    typedef __bf16 bf16x2 __attribute__((ext_vector_type(2)));
    bf16x2 v = __builtin_amdgcn_cvt_pk_bf16_f32(a, b);
    return __builtin_bit_cast(unsigned, v);
#else
    return (unsigned)bf16_rne(a) | ((unsigned)bf16_rne(b) << 16);
#endif
}

// Branch-free scalar gelu (A&S 7.1.26, |err_erf|<1.5e-7) — special blocks only.
__device__ __forceinline__ float gelu_f(float x) {
    float ax = fabsf(x);
    float z  = ax * 0.7071067811865476f;
    float t  = __builtin_amdgcn_rcpf(fmaf(0.3275911f, z, 1.0f));
    float p  = t * fmaf(t, fmaf(t, fmaf(t, fmaf(t, 1.061405429f, -1.453152027f),
                                        1.421413741f), -0.284496736f), 0.254829592f);
    float e  = __expf(-z * z);
    float hx = 0.5f * ax;
    return fmaf(0.5f, x, hx) - hx * p * e;
}
// Packed 2-wide gelu: same formula elementwise; fp32 vector ops lower to v_pk_*.
__device__ __forceinline__ f2v gelu2(f2v x) {
    f2v ax; ax.x = fabsf(x.x); ax.y = fabsf(x.y);
    f2v z   = ax * 0.7071067811865476f;
    f2v den = z * 0.3275911f + 1.0f;
    f2v t;  t.x = __builtin_amdgcn_rcpf(den.x); t.y = __builtin_amdgcn_rcpf(den.y);
    f2v p = t * (t * (t * (t * (t * 1.061405429f + (-1.453152027f)) + 1.421413741f)
              + (-0.284496736f)) + 0.254829592f);
    f2v nz2 = -z * z;
    f2v e;  e.x = __expf(nz2.x); e.y = __expf(nz2.y);
    f2v hx = ax * 0.5f;
    return (x * 0.5f + hx) - (hx * p) * e;
}

// One prep kernel: W2 (fp32 E'/F'), Wbf (split-bf16 B-operand layout), RB (row-0 bias map).
__global__ void prep_all(const float* __restrict__ wr, const float* __restrict__ wi,
                         const float* __restrict__ cw,
                         const float* __restrict__ br, const float* __restrict__ bi,
                         float* __restrict__ W2, unsigned short* __restrict__ Wbf,
                         float* __restrict__ RB) {
    int bid = blockIdx.x;
    if (bid < 512) {
        int idx = bid * 256 + threadIdx.x;              // 131072
        {   // W2[l][which][i][o] = 0.5*(cw[l][o][i] + (which? wi:wr)[l][i][o])
            int l = idx >> 15, which = (idx >> 14) & 1, i = (idx >> 7) & 127, o = idx & 127;
            const float* w = which ? wi : wr;
            W2[idx] = 0.5f * (cw[(l << 14) + (o << 7) + i] + w[(l << 14) + (i << 7) + o]);
        }
        {   // Wbf[l][kc][mat][half][quad][col][j]
            int t = idx;
            int j = t & 7, col = (t >> 3) & 127, quad = (t >> 10) & 3;
            int m2 = (t >> 12) & 1, kc = (t >> 13) & 3, l = t >> 15;
            int k = kc * 32 + quad * 8 + j;
            const float* w = m2 ? wi : wr;
            float v = 0.5f * (cw[(l << 14) + (col << 7) + k] + w[(l << 14) + (k << 7) + col]);
            unsigned short hi = bf16_rne(v);
            unsigned short lo = bf16_rne(v - bf16_tof(hi));
            int base = (l * 4 + kc) * 16384;
            Wbf[base + (((m2 * 2 + 0) * 4 + quad) * 128 + col) * 8 + j] = hi;
            Wbf[base + (((m2 * 2 + 1) * 4 + quad) * 128 + col) * 8 + j] = lo;
        }
    } else {
        int idx = (bid - 512) * 256 + threadIdx.x;      // 131072 = 4*256*128
        int l = idx >> 15, c = (idx >> 7) & 255, o = idx & 127;
        float v;
        if (c == 0) {
            v = br[(l << 7) + o];
        } else {
            float s = 0.0f;
            for (int k = 1; k < 128; k++) {
                int m = (k * c) & 255;
                s += sinf(0.024543692952156857f * (float)m);  // pi/128
            }
            v = -bi[(l << 7) + o] * s * 0.0078125f;
        }
        RB[idx] = v;
    }
}

// Abuf layout (ushort): [sd2][kt4][half2][pair32][qj(APAD)]; qj = k&31.
#define APAD 40
#define A_IDX(sd, kt, hf, pair, qj) ((((((sd)*4 + (kt))*2 + (hf))*32 + (pair))*APAD) + (qj))
// Wbf chunk-relative index: [mat2][half2][quad4][col128][j8]
#define W_IDX(m2, hf, quad, col) (((((m2)*2 + (hf))*4 + (quad))*128 + (col))*8)

// K-loop core (per wave: M=32 pairs x N=16 och). U += E'^T s, V += F'^T d (3-term split).
// Two half-passes per kc (U then V) keep peak live fragments at 24 regs (no spill).
__device__ __forceinline__ void layer_core(const unsigned short* Abuf,
        const unsigned short* __restrict__ Wl, int wv, int l15, int quad,
        f4v U[2], f4v V[2])
{
    U[0] = (f4v){0.f, 0.f, 0.f, 0.f}; U[1] = (f4v){0.f, 0.f, 0.f, 0.f};
    V[0] = (f4v){0.f, 0.f, 0.f, 0.f}; V[1] = (f4v){0.f, 0.f, 0.f, 0.f};
    #pragma unroll
    for (int kc = 0; kc < 4; kc++) {
        {   // ---- U pass: sd=0 (s rows), E' (m2=0) ----
            s8v b0 = *(const s8v*)&Wl[kc * 16384 + W_IDX(0, 0, quad, wv * 16 + l15)];
            s8v b1 = *(const s8v*)&Wl[kc * 16384 + W_IDX(0, 1, quad, wv * 16 + l15)];
            s8v ah0 = *(const s8v*)&Abuf[A_IDX(0, kc, 0, l15,      quad * 8)];
            s8v ah1 = *(const s8v*)&Abuf[A_IDX(0, kc, 0, 16 + l15, quad * 8)];
            s8v al0 = *(const s8v*)&Abuf[A_IDX(0, kc, 1, l15,      quad * 8)];
            s8v al1 = *(const s8v*)&Abuf[A_IDX(0, kc, 1, 16 + l15, quad * 8)];
            U[0] = __builtin_amdgcn_mfma_f32_16x16x32_bf16(ah0, b0, U[0], 0, 0, 0);
            U[1] = __builtin_amdgcn_mfma_f32_16x16x32_bf16(ah1, b0, U[1], 0, 0, 0);
            U[0] = __builtin_amdgcn_mfma_f32_16x16x32_bf16(ah0, b1, U[0], 0, 0, 0);
            U[1] = __builtin_amdgcn_mfma_f32_16x16x32_bf16(ah1, b1, U[1], 0, 0, 0);
            U[0] = __builtin_amdgcn_mfma_f32_16x16x32_bf16(al0, b0, U[0], 0, 0, 0);
            U[1] = __builtin_amdgcn_mfma_f32_16x16x32_bf16(al1, b0, U[1], 0, 0, 0);
        }
        {   // ---- V pass: sd=1 (d rows), F' (m2=1) ----
            s8v b0 = *(const s8v*)&Wl[kc * 16384 + W_IDX(1, 0, quad, wv * 16 + l15)];
            s8v b1 = *(const s8v*)&Wl[kc * 16384 + W_IDX(1, 1, quad, wv * 16 + l15)];
            s8v ah0 = *(const s8v*)&Abuf[A_IDX(1, kc, 0, l15,      quad * 8)];
            s8v ah1 = *(const s8v*)&Abuf[A_IDX(1, kc, 0, 16 + l15, quad * 8)];
            s8v al0 = *(const s8v*)&Abuf[A_IDX(1, kc, 1, l15,      quad * 8)];
            s8v al1 = *(const s8v*)&Abuf[A_IDX(1, kc, 1, 16 + l15, quad * 8)];
            V[0] = __builtin_amdgcn_mfma_f32_16x16x32_bf16(ah0, b0, V[0], 0, 0, 0);
            V[1] = __builtin_amdgcn_mfma_f32_16x16x32_bf16(ah1, b0, V[1], 0, 0, 0);
            V[0] = __builtin_amdgcn_mfma_f32_16x16x32_bf16(ah0, b1, V[0], 0, 0, 0);
            V[1] = __builtin_amdgcn_mfma_f32_16x16x32_bf16(ah1, b1, V[1], 0, 0, 0);
            V[0] = __builtin_amdgcn_mfma_f32_16x16x32_bf16(al0, b0, V[0], 0, 0, 0);
            V[1] = __builtin_amdgcn_mfma_f32_16x16x32_bf16(al1, b0, V[1], 0, 0, 0);
        }
    }
}

__global__ __launch_bounds__(512, 4) void fno_fused(
        const float* __restrict__ x,
        const float* __restrict__ w_in, const float* __restrict__ b_in,
        const unsigned short* __restrict__ Wbf,
        const float* __restrict__ W2,
        const float* __restrict__ RB,
        const float* __restrict__ cb,
        const float* __restrict__ wo, const float* __restrict__ bo,
        float* __restrict__ out)
{
    __shared__ unsigned short Abuf[2 * 4 * 2 * 32 * APAD];   // 40 KB

    int bid = blockIdx.x;
    int tid = threadIdx.x;

    if (bid >= 4096) {
        // --- special: self-paired pixels (b,0,0) and (b,128,0), fp32 path ---
        float* Hs = (float*)Abuf;
        int b2 = bid - 4096;
        int o = tid & 127;
        int rowp = (tid < 128) ? 0 : 128;
        float hval = 0.0f;
        if (tid < 256) {
            float acc = b_in[o];
            #pragma unroll
            for (int c = 0; c < 3; c++)
                acc = fmaf(x[((b2 * 3 + c) << 16) + (rowp << 8)], w_in[c * 128 + o], acc);
            hval = gelu_f(acc);
        }
        for (int l = 0; l < 4; l++) {
            __syncthreads();
            if (tid < 256) Hs[tid] = hval;
            __syncthreads();
            if (tid < 256) {
                const float* W2l = W2 + l * 32768;          // E' (which=0) plane
                const float* hb = Hs + ((tid < 128) ? 0 : 128);
                float a2 = 0.0f;
                for (int i = 0; i < 128; i++) a2 = fmaf(W2l[(i << 7) + o], hb[i], a2);
                a2 = 2.0f * a2 + cb[l * 128 + o];
                if (tid < 128) a2 += RB[l * 32768 + o];     // row 0, col 0
                hval = gelu_f(a2);
            }
        }
        __syncthreads();
        if (tid < 256) Hs[tid] = hval * wo[o];
        __syncthreads();
        #pragma unroll
        for (int off = 64; off >= 1; off >>= 1) {
            if (tid < 256 && (tid & 127) < off) Hs[tid] += Hs[tid + off];
            __syncthreads();
        }
        if (tid < 256 && (tid & 127) == 0) out[(b2 << 16) + (rowp << 8)] = gelu_f(Hs[tid] + bo[0]);
        return;
    }

    int b = bid >> 10;
    int rem = bid & 1023;
    int r, c0, rq;
    bool rowzero;
    if (rem < 1016) {
        r = 1 + (rem >> 3);
        c0 = (rem & 7) << 5;
        rq = 256 - r;
        rowzero = false;
    } else {
        int idx2 = rem - 1016;
        r = (idx2 < 4) ? 0 : 128;
        c0 = 1 + ((idx2 & 3) << 5);
        rq = r;
        rowzero = (r == 0);
    }

    // ---- lin_in + stage A: h = gelu(x*Win+bin); s/d split-bf16 into Abuf ----
    {
        int j2 = tid >> 4;                  // pair 0..31
        int seg = tid & 15;                 // 8-ch segment
        int ch0 = seg << 3;
        int cp = c0 + j2;
        int cq = (256 - cp) & 255;
        float xp[3], xq[3];
        #pragma unroll
        for (int c = 0; c < 3; c++) {
            xp[c] = x[((b * 3 + c) << 16) + (r << 8) + cp];
            xq[c] = x[((b * 3 + c) << 16) + (rq << 8) + cq];
        }
        int kt = seg >> 2;
        int qj = (seg & 3) << 3;
        alignas(16) unsigned short sh[8], sl[8], dh[8], dl[8];
        #pragma unroll
        for (int jj = 0; jj < 8; jj++) {
            int d = ch0 + jj;
            float bv = b_in[d];
            f2v acc2; acc2.x = bv; acc2.y = bv;
            #pragma unroll
            for (int c = 0; c < 3; c++) {
                float w = w_in[c * 128 + d];
                f2v xv; xv.x = xp[c]; xv.y = xq[c];
                acc2 = xv * w + acc2;
            }
            f2v g = gelu2(acc2);
            float s = g.x + g.y, dd = g.x - g.y;
            unsigned hpk = pk_bf16(s, dd);
            f2v res;
            res.x = s  - __uint_as_float(hpk << 16);
            res.y = dd - __uint_as_float(hpk & 0xFFFF0000u);
            unsigned lpk = pk_bf16(res.x, res.y);
            sh[jj] = (unsigned short)hpk; dh[jj] = (unsigned short)(hpk >> 16);
            sl[jj] = (unsigned short)lpk; dl[jj] = (unsigned short)(lpk >> 16);
        }
        *(s8v*)&Abuf[A_IDX(0, kt, 0, j2, qj)] = *(const s8v*)sh;
        *(s8v*)&Abuf[A_IDX(0, kt, 1, j2, qj)] = *(const s8v*)sl;
        *(s8v*)&Abuf[A_IDX(1, kt, 0, j2, qj)] = *(const s8v*)dh;
        *(s8v*)&Abuf[A_IDX(1, kt, 1, j2, qj)] = *(const s8v*)dl;
    }

    int lane = tid & 63;
    int wv = tid >> 6;                      // wave -> 16-och strip
    int l15 = lane & 15;
    int quad = lane >> 4;
    int och = wv * 16 + l15;                // this thread's out-channel
    int rkt = wv >> 1;                      // restage kt
    int rqj = ((wv & 1) << 4) + l15;        // restage qj

    // ---- layers 0..2: GEMM + epilogue + restage ----
    for (int l = 0; l < 3; l++) {
        __syncthreads();                    // Abuf writes visible
        f4v U[2], V[2];
        layer_core(Abuf, Wbf + l * 65536, wv, l15, quad, U, V);
        __syncthreads();                    // all Abuf reads done before restage

        const float* RBl = RB + l * 32768;
        float cbv = cb[l * 128 + och];
        #pragma unroll
        for (int mt = 0; mt < 2; mt++)
            #pragma unroll
            for (int rg = 0; rg < 4; rg++) {
                int pair = mt * 16 + quad * 4 + rg;
                int colp = c0 + pair;
                int colq = (256 - colp) & 255;
                float u = U[mt][rg], v = V[mt][rg];
                f2v bpq; bpq.x = u + v + cbv; bpq.y = u - v + cbv;
                if (rowzero) {
                    bpq.x += RBl[(colp << 7) + och];
                    bpq.y += RBl[(colq << 7) + och];
                }
                f2v g = gelu2(bpq);
                float s = g.x + g.y, dd = g.x - g.y;
                unsigned hpk = pk_bf16(s, dd);
                f2v res;
                res.x = s  - __uint_as_float(hpk << 16);
                res.y = dd - __uint_as_float(hpk & 0xFFFF0000u);
                unsigned lpk = pk_bf16(res.x, res.y);
                Abuf[A_IDX(0, rkt, 0, pair, rqj)] = (unsigned short)hpk;
                Abuf[A_IDX(1, rkt, 0, pair, rqj)] = (unsigned short)(hpk >> 16);
                Abuf[A_IDX(0, rkt, 1, pair, rqj)] = (unsigned short)lpk;
                Abuf[A_IDX(1, rkt, 1, pair, rqj)] = (unsigned short)(lpk >> 16);
            }
    }

    // ---- layer 3 (peeled): GEMM + epilogue -> lin_out partials ----
    float pp[8], pq[8];                     // idx = mt*4+rg
    {
        __syncthreads();
        f4v U[2], V[2];
        layer_core(Abuf, Wbf + 3 * 65536, wv, l15, quad, U, V);
        __syncthreads();                    // all Abuf reads done (Pb reuse below)

        float wov = wo[och];
        const float* RBl = RB + 3 * 32768;
        float cbv = cb[3 * 128 + och];
        #pragma unroll
        for (int mt = 0; mt < 2; mt++)
            #pragma unroll
            for (int rg = 0; rg < 4; rg++) {
                int pair = mt * 16 + quad * 4 + rg;
                int colp = c0 + pair;
                int colq = (256 - colp) & 255;
                float u = U[mt][rg], v = V[mt][rg];
                f2v bpq; bpq.x = u + v + cbv; bpq.y = u - v + cbv;
                if (rowzero) {
                    bpq.x += RBl[(colp << 7) + och];
                    bpq.y += RBl[(colq << 7) + och];
                }
                f2v g = gelu2(bpq);
                pp[mt * 4 + rg] = g.x * wov;
                pq[mt * 4 + rg] = g.y * wov;
            }
    }

    // ---- lin_out: reduce over l15 (16 lanes) then across 8 waves via LDS ----
    #pragma unroll
    for (int i = 0; i < 8; i++) {
        #pragma unroll
        for (int m = 1; m <= 8; m <<= 1) {
            pp[i] += __shfl_xor(pp[i], m, 64);
            pq[i] += __shfl_xor(pq[i], m, 64);
        }
    }
    float* Pb = (float*)Abuf;               // [2][32 pairs][8 wv]
    if (l15 == 0) {
        #pragma unroll
        for (int mt = 0; mt < 2; mt++)
            #pragma unroll
            for (int rg = 0; rg < 4; rg++) {
                int pair = mt * 16 + quad * 4 + rg;
                Pb[(pair << 3) + wv]        = pp[mt * 4 + rg];
                Pb[256 + (pair << 3) + wv]  = pq[mt * 4 + rg];
            }
    }
    __syncthreads();
    if (tid < 64) {
        int pqsel = tid >> 5;
        int pair = tid & 31;
        const float* pb = Pb + pqsel * 256 + (pair << 3);
        float ssum = ((pb[0] + pb[1]) + (pb[2] + pb[3])) +
                     ((pb[4] + pb[5]) + (pb[6] + pb[7])) + bo[0];
        int colp = c0 + pair;
        int col = pqsel ? ((256 - colp) & 255) : colp;
        int row = pqsel ? rq : r;
        out[(b << 16) + (row << 8) + col] = gelu_f(ssum);
    }
}

extern "C" void kernel_launch(void* const* d_in, const int* in_sizes, int n_in,
                              void* d_out, int out_size, void* d_ws, size_t ws_size,
                              hipStream_t stream) {
    const float* x         = (const float*)d_in[0];
    const float* lin_in_w  = (const float*)d_in[1];
    const float* lin_in_b  = (const float*)d_in[2];
    const float* wr        = (const float*)d_in[3];
    const float* wi        = (const float*)d_in[4];
    const float* br        = (const float*)d_in[5];
    const float* bi        = (const float*)d_in[6];
    const float* cw        = (const float*)d_in[7];
    const float* cb        = (const float*)d_in[8];
    const float* lin_out_w = (const float*)d_in[9];
    const float* lin_out_b = (const float*)d_in[10];
    float* out = (float*)d_out;

    size_t need = (size_t)(W2_FLOATS + RB_FLOATS) * sizeof(float)
                + (size_t)WBF_USHORTS * sizeof(unsigned short);
    if (ws_size < need) return;
    float* ws = (float*)d_ws;
    float* W2 = ws;
    float* RB = W2 + W2_FLOATS;
    unsigned short* Wbf = (unsigned short*)(RB + RB_FLOATS);

    prep_all<<<1024, 256, 0, stream>>>(wr, wi, cw, br, bi, W2, Wbf, RB);
    fno_fused<<<4100, 512, 0, stream>>>(x, lin_in_w, lin_in_b, Wbf, W2, RB,
                                        cb, lin_out_w, lin_out_b, out);
}